// Round 15
// baseline (423.055 us; speedup 1.0000x reference)
//
#include <hip/hip_runtime.h>

// Problem constants: B=128, L=512, D=256, H=128, 4H=512, both dirs fused NG=1024
#define NB 128
#define NL 512
#define ND 256
#define NG 1024

typedef __attribute__((ext_vector_type(8))) short bfv8;
typedef __attribute__((ext_vector_type(4))) float f32x4;

#define LOG2E 1.4426950408889634f
#define NSCALE (-1.4426950408889634f)   // i,f,o gate rows: t = -x*log2e
#define GSCALE (2.8853900817779268f)    // g gate rows: t = 2x*log2e

__device__ __forceinline__ unsigned short f2bf(float f) {
    unsigned u = __float_as_uint(f);
    u += 0x7fffu + ((u >> 16) & 1u);   // round-to-nearest-even
    return (unsigned short)(u >> 16);
}
__device__ __forceinline__ float bf2f(unsigned short u) {
    return __uint_as_float(((unsigned)u) << 16);
}

// ---------------------------------------------------------------------------
// 1) convert+transpose: xbt[l*128+b][d] = bf16(x[b][l][d])
// ---------------------------------------------------------------------------
__global__ __launch_bounds__(256) void convert_kernel(const float* __restrict__ x,
                                                      unsigned short* __restrict__ xbt) {
    size_t t = (size_t)blockIdx.x * 256 + threadIdx.x;
    size_t e = t * 4;                       // flat idx into x, 4 floats per thread
    int d = (int)(e & 255u);
    int l = (int)((e >> 8) & 511u);
    int b = (int)(e >> 17);
    float4 v = *(const float4*)(x + e);
    ushort4 o;
    o.x = f2bf(v.x); o.y = f2bf(v.y); o.z = f2bf(v.z); o.w = f2bf(v.w);
    *(ushort4*)(xbt + ((size_t)(l * NB + b)) * ND + d) = o;
}

// ---------------------------------------------------------------------------
// 2) fold: Weff[g][k] = scale(g) * sum_d Wih[row(g)][d] * W_proj[d][k]
//    Rows reordered g = dir*512 + hid*4 + gate; gate order i,f,g,o.
//    EXP2-DOMAIN scaling folded in: i,f,o rows x(-log2e), g rows x(+2 log2e)
// ---------------------------------------------------------------------------
__global__ __launch_bounds__(256) void fold_kernel(const float* __restrict__ Wproj,
                                                   const float* __restrict__ bproj,
                                                   const float* __restrict__ Wih_f,
                                                   const float* __restrict__ b_f,
                                                   const float* __restrict__ Wih_b,
                                                   const float* __restrict__ b_b,
                                                   unsigned short* __restrict__ weff,
                                                   float* __restrict__ beff) {
    int g = blockIdx.x;            // 0..1023 (reordered output row)
    int k = threadIdx.x;           // 0..255
    int dirg = g >> 9;
    int rem  = g & 511;
    int hidg = rem >> 2;
    int gate = rem & 3;
    int srcrow = gate * 128 + hidg;
    float scale = (gate == 2) ? GSCALE : NSCALE;
    const float* Wih = dirg ? (Wih_b + (size_t)srcrow * ND) : (Wih_f + (size_t)srcrow * ND);
    float acc = 0.f;
    for (int d = 0; d < ND; ++d)
        acc += Wih[d] * Wproj[(size_t)d * ND + k];
    weff[(size_t)g * ND + k] = f2bf(acc * scale);
    if (k == 0) {
        float ab = dirg ? b_b[srcrow] : b_f[srcrow];
        for (int d = 0; d < ND; ++d) ab += Wih[d] * bproj[d];
        beff[g] = ab * scale;
    }
}

// ---------------------------------------------------------------------------
// 3) pre-GEMM: C[r][g] = bf16( A[r][:] . Bw[g][:] + bias[g] )
//    128x128 tile, BK=32, 4 waves (2x2), 16x16x32 bf16 MFMA, XOR-swizzled LDS
// ---------------------------------------------------------------------------
__global__ __launch_bounds__(256, 2) void gemm_pre(const unsigned short* __restrict__ A,
                                                   const unsigned short* __restrict__ Bw,
                                                   const float* __restrict__ bias,
                                                   unsigned short* __restrict__ C) {
    __shared__ unsigned short As[128 * 32];
    __shared__ unsigned short Bs[128 * 32];
    const int tid = threadIdx.x;
    const int lane = tid & 63;
    const int wid = tid >> 6;
    const int m0 = blockIdx.y * 128;
    const int n0 = blockIdx.x * 128;
    const int wm = (wid >> 1) * 64;
    const int wn = (wid & 1) * 64;

    f32x4 acc[4][4] = {};

    const int row0 = tid >> 2;               // 0..63
    const int row1 = row0 + 64;
    const int co = (tid & 3) * 8;            // element col offset (8 bf16 = 16B)
    const int sw = (((tid & 3) << 4) ^ ((row0 & 3) << 4)) >> 1;

    bfv8 ra0 = *(const bfv8*)(A + (size_t)(m0 + row0) * ND + co);
    bfv8 ra1 = *(const bfv8*)(A + (size_t)(m0 + row1) * ND + co);
    bfv8 rb0 = *(const bfv8*)(Bw + (size_t)(n0 + row0) * ND + co);
    bfv8 rb1 = *(const bfv8*)(Bw + (size_t)(n0 + row1) * ND + co);

    for (int it = 0; it < 8; ++it) {
        __syncthreads();
        *(bfv8*)(As + row0 * 32 + sw) = ra0;
        *(bfv8*)(As + row1 * 32 + sw) = ra1;
        *(bfv8*)(Bs + row0 * 32 + sw) = rb0;
        *(bfv8*)(Bs + row1 * 32 + sw) = rb1;
        const int k1 = ((it + 1) & 7) * 32;
        ra0 = *(const bfv8*)(A + (size_t)(m0 + row0) * ND + k1 + co);
        ra1 = *(const bfv8*)(A + (size_t)(m0 + row1) * ND + k1 + co);
        rb0 = *(const bfv8*)(Bw + (size_t)(n0 + row0) * ND + k1 + co);
        rb1 = *(const bfv8*)(Bw + (size_t)(n0 + row1) * ND + k1 + co);
        __syncthreads();

        const int r = lane & 15;
        const int kq = lane >> 4;
        bfv8 af[4], bfr[4];
        #pragma unroll
        for (int m = 0; m < 4; ++m) {
            int rw = wm + m * 16 + r;
            af[m] = *(const bfv8*)(As + rw * 32 + (((kq << 4) ^ ((rw & 3) << 4)) >> 1));
        }
        #pragma unroll
        for (int n = 0; n < 4; ++n) {
            int rw = wn + n * 16 + r;
            bfr[n] = *(const bfv8*)(Bs + rw * 32 + (((kq << 4) ^ ((rw & 3) << 4)) >> 1));
        }
        #pragma unroll
        for (int m = 0; m < 4; ++m)
            #pragma unroll
            for (int n = 0; n < 4; ++n)
                acc[m][n] = __builtin_amdgcn_mfma_f32_16x16x32_bf16(af[m], bfr[n], acc[m][n], 0, 0, 0);
    }

    const int r = lane & 15;
    const int rq = lane >> 4;
    #pragma unroll
    for (int n = 0; n < 4; ++n) {
        int col = n0 + wn + n * 16 + r;
        float bv = bias[col];
        #pragma unroll
        for (int m = 0; m < 4; ++m) {
            #pragma unroll
            for (int v = 0; v < 4; ++v) {
                int rowg = m0 + wm + m * 16 + rq * 4 + v;
                C[(size_t)rowg * NG + col] = f2bf(acc[m][n][v] + bv);
            }
        }
    }
}

// ---------------------------------------------------------------------------
// 4) LSTM scan: 4-WAVE (256-thread) blocks, 2 hid-groups per wave.
//    r14 analysis: per-SIMD issue-bound (2 waves x ~330cy issue = 660cy/SIMD
//    + chain tails = 1214cy wall). This config: 1 wave/SIMD issuing ~430cy
//    (32 MFMAs over 8 col-tiles x 4 ktiles, A-frags SHARED across all 8
//    tiles; 2 ACTs/lane), halved LDS return (16KB/step), narrower barrier.
//    Same 128 MFMAs/CU/step. Regs ~220/wave, budget 512 at 1 wave/SIMD.
//    h stored bf16 to hs workspace (ln reads bf16 -> saves 64MB traffic).
//    Keeps: 16x A-replication (broadcast ds_read), exp2/rcp lean ACT,
//    saddr+v_off pre loads (depth-2 prefetch), ONE raw barrier/step
//    (counted vmcnt), LDS pin >80KiB -> 1 block/CU + full reg budget.
// ---------------------------------------------------------------------------
struct ScanSM {
    unsigned short h[2][136];      // [buf][hid] bf16
    char pin[81700];               // total 82244 B > 81920 -> 1 block/CU
};

#define MFMA16(a, b, c) __builtin_amdgcn_mfma_f32_16x16x32_bf16((a), (b), (c), 0, 0, 0)

// ACT for one hid-group: inputs 4 gate accs, pre uint2, cell state, hid, NXTB
#define ACT2(AI, AF, AG, AO, PP, CC, HID, NXTB)                                \
    {                                                                          \
        float pi = __uint_as_float(PP.x << 16);                                \
        float pf = __uint_as_float(PP.x & 0xffff0000u);                        \
        float pg = __uint_as_float(PP.y << 16);                                \
        float po = __uint_as_float(PP.y & 0xffff0000u);                        \
        float ia = __builtin_amdgcn_rcpf(1.f + __builtin_amdgcn_exp2f(AI[0] + pi)); \
        float fa = __builtin_amdgcn_rcpf(1.f + __builtin_amdgcn_exp2f(AF[0] + pf)); \
        float rg = __builtin_amdgcn_rcpf(1.f + __builtin_amdgcn_exp2f(AG[0] + pg)); \
        float oa = __builtin_amdgcn_rcpf(1.f + __builtin_amdgcn_exp2f(AO[0] + po)); \
        float ga = fmaf(-2.f, rg, 1.f);                                        \
        CC = fmaf(fa, CC, ia * ga);                                            \
        float rc = __builtin_amdgcn_rcpf(1.f + __builtin_amdgcn_exp2f(CC * GSCALE)); \
        float th = fmaf(-2.f, rc, 1.f);                                        \
        unsigned short us = f2bf(oa * th);                                     \
        if (q == 0) {                                                          \
            sm.h[NXTB][HID] = us;                                              \
            hsrow[(size_t)tt * 256 + HID] = us;                                \
        }                                                                      \
    }

#define STEP(S, CURB, NXTB)                                                    \
  {                                                                            \
    int rr = (S) + 2; if (rr > 511) rr = 511;          /* uniform SALU */      \
    int tts = dirs ? (511 - rr) : rr;                                          \
    const unsigned short* rowp = pdb + (size_t)tts * (NB * NG);                \
    uint2 nxa = *(const uint2*)(rowp + hid4a);         /* saddr + v_off */     \
    uint2 nxb = *(const uint2*)(rowp + hid4b);                                 \
    bfv8 ha0 = *(const bfv8*)&sm.h[CURB][q * 8];                               \
    bfv8 ha1 = *(const bfv8*)&sm.h[CURB][32 + q * 8];                          \
    bfv8 ha2 = *(const bfv8*)&sm.h[CURB][64 + q * 8];                          \
    bfv8 ha3 = *(const bfv8*)&sm.h[CURB][96 + q * 8];                          \
    f32x4 z = {0.f, 0.f, 0.f, 0.f};                                            \
    f32x4 aA0 = MFMA16(ha0, bfr[0][0], z);                                     \
    f32x4 aA1 = MFMA16(ha0, bfr[1][0], z);                                     \
    f32x4 aA2 = MFMA16(ha0, bfr[2][0], z);                                     \
    f32x4 aA3 = MFMA16(ha0, bfr[3][0], z);                                     \
    f32x4 aB0 = MFMA16(ha0, bfr[4][0], z);                                     \
    f32x4 aB1 = MFMA16(ha0, bfr[5][0], z);                                     \
    f32x4 aB2 = MFMA16(ha0, bfr[6][0], z);                                     \
    f32x4 aB3 = MFMA16(ha0, bfr[7][0], z);                                     \
    aA0 = MFMA16(ha1, bfr[0][1], aA0); aA1 = MFMA16(ha1, bfr[1][1], aA1);      \
    aA2 = MFMA16(ha1, bfr[2][1], aA2); aA3 = MFMA16(ha1, bfr[3][1], aA3);      \
    aB0 = MFMA16(ha1, bfr[4][1], aB0); aB1 = MFMA16(ha1, bfr[5][1], aB1);      \
    aB2 = MFMA16(ha1, bfr[6][1], aB2); aB3 = MFMA16(ha1, bfr[7][1], aB3);      \
    aA0 = MFMA16(ha2, bfr[0][2], aA0); aA1 = MFMA16(ha2, bfr[1][2], aA1);      \
    aA2 = MFMA16(ha2, bfr[2][2], aA2); aA3 = MFMA16(ha2, bfr[3][2], aA3);      \
    aB0 = MFMA16(ha2, bfr[4][2], aB0); aB1 = MFMA16(ha2, bfr[5][2], aB1);      \
    aB2 = MFMA16(ha2, bfr[6][2], aB2); aB3 = MFMA16(ha2, bfr[7][2], aB3);      \
    aA0 = MFMA16(ha3, bfr[0][3], aA0); aA1 = MFMA16(ha3, bfr[1][3], aA1);      \
    aA2 = MFMA16(ha3, bfr[2][3], aA2); aA3 = MFMA16(ha3, bfr[3][3], aA3);      \
    aB0 = MFMA16(ha3, bfr[4][3], aB0); aB1 = MFMA16(ha3, bfr[5][3], aB1);      \
    aB2 = MFMA16(ha3, bfr[6][3], aB2); aB3 = MFMA16(ha3, bfr[7][3], aB3);      \
    int tt = dirs ? (511 - (S)) : (S);                                         \
    ACT2(aA0, aA1, aA2, aA3, pPa0, c0a, hidA, NXTB)                            \
    ACT2(aB0, aB1, aB2, aB3, pPb0, c0b, hidB, NXTB)                            \
    pPa0 = pPa1; pPa1 = nxa;                                                   \
    pPb0 = pPb1; pPb1 = nxb;                                                   \
    __builtin_amdgcn_sched_barrier(0);                                         \
    asm volatile("s_waitcnt lgkmcnt(0)");                                      \
    __builtin_amdgcn_s_barrier();                                              \
    __builtin_amdgcn_sched_barrier(0);                                         \
  }

__global__ void __launch_bounds__(256)
scan_kernel(const unsigned short* __restrict__ pre,
            const float* __restrict__ Whh_f,
            const float* __restrict__ Whh_b,
            unsigned short* __restrict__ hs) {
    const int b    = blockIdx.x;         // batch 0..127
    const int dirs = blockIdx.y;         // 0 fwd, 1 bwd (kernel-scalar)
    const int tid  = threadIdx.x;
    const int w    = tid >> 6;           // wave id 0..3
    const int lane = tid & 63;
    const int r    = lane & 15;          // frag col -> hid sub-index
    const int q    = lane >> 4;          // frag k-group
    const int hidA = 16 * w + r;         // hid-group 0: hids 0..63
    const int hidB = hidA + 64;          // hid-group 1: hids 64..127
    const int hid4a = hidA * 4;          // element offset of lane's uint2
    const int hid4b = hidB * 4;

    __shared__ ScanSM sm;

    // ---- persistent B-fragments: Whh (f32) -> bf16 with exp2-domain scale --
    // bfr[hg*4+g][kk]: col tile = gate g, hids 16w+64hg .. +15
    const float* __restrict__ Wd = dirs ? Whh_b : Whh_f;
    bfv8 bfr[8][4];
    #pragma unroll
    for (int hg = 0; hg < 2; ++hg) {
        const int hh = 16 * w + 64 * hg + r;
        #pragma unroll
        for (int g = 0; g < 4; ++g) {
            const float wscale = (g == 2) ? GSCALE : NSCALE;
            #pragma unroll
            for (int kk = 0; kk < 4; ++kk) {
                const float* src = Wd + (size_t)(g * 128 + hh) * 128 + kk * 32 + q * 8;
                float4 lo = *(const float4*)(src);
                float4 hi = *(const float4*)(src + 4);
                bfv8 v;
                v[0] = (short)f2bf(lo.x * wscale); v[1] = (short)f2bf(lo.y * wscale);
                v[2] = (short)f2bf(lo.z * wscale); v[3] = (short)f2bf(lo.w * wscale);
                v[4] = (short)f2bf(hi.x * wscale); v[5] = (short)f2bf(hi.y * wscale);
                v[6] = (short)f2bf(hi.z * wscale); v[7] = (short)f2bf(hi.w * wscale);
                bfr[hg * 4 + g][kk] = v;
            }
        }
    }

    // ---- zero h buf 0 ----
    if (q == 0) { sm.h[0][hidA] = 0; sm.h[0][hidB] = 0; }

    float c0a = 0.f, c0b = 0.f;

    // ---- uniform bases: pre row base (dir half), hs batch base ----
    const unsigned short* pdb = pre + (size_t)b * NG + dirs * 512;
    unsigned short* hsrow = hs + (size_t)b * NL * 256 + dirs * 128;

    int t0 = dirs ? 511 : 0;
    int t1 = dirs ? 510 : 1;
    uint2 pPa0 = *(const uint2*)(pdb + (size_t)t0 * (NB * NG) + hid4a);
    uint2 pPb0 = *(const uint2*)(pdb + (size_t)t0 * (NB * NG) + hid4b);
    uint2 pPa1 = *(const uint2*)(pdb + (size_t)t1 * (NB * NG) + hid4a);
    uint2 pPb1 = *(const uint2*)(pdb + (size_t)t1 * (NB * NG) + hid4b);
    __syncthreads();

    for (int s = 0; s < 512; s += 2) {
        STEP(s, 0, 1)
        STEP(s + 1, 1, 0)
    }
}

// ---------------------------------------------------------------------------
// 5) LayerNorm: read bf16 hs, write f32 out; one wave per 256-wide row
// ---------------------------------------------------------------------------
__global__ __launch_bounds__(256) void ln_kernel(const unsigned short* __restrict__ hs,
                                                 float* __restrict__ out,
                                                 const float* __restrict__ gamma,
                                                 const float* __restrict__ beta) {
    int row = blockIdx.x * 4 + (threadIdx.x >> 6);
    int lane = threadIdx.x & 63;
    const ushort4 hv = ((const ushort4*)(hs + (size_t)row * 256))[lane];
    float a = bf2f(hv.x), bb = bf2f(hv.y), c = bf2f(hv.z), d = bf2f(hv.w);
    float s = (a + bb) + (c + d);
    float s2 = (a * a + bb * bb) + (c * c + d * d);
    #pragma unroll
    for (int o = 32; o > 0; o >>= 1) {
        s += __shfl_xor(s, o);
        s2 += __shfl_xor(s2, o);
    }
    float mu = s * (1.f / 256.f);
    float var = s2 * (1.f / 256.f) - mu * mu;
    float rs = rsqrtf(var + 1e-5f);
    float4 gv = ((const float4*)gamma)[lane];
    float4 bv = ((const float4*)beta)[lane];
    float4 rr;
    rr.x = (a - mu) * rs * gv.x + bv.x;
    rr.y = (bb - mu) * rs * gv.y + bv.y;
    rr.z = (c - mu) * rs * gv.z + bv.z;
    rr.w = (d - mu) * rs * gv.w + bv.w;
    ((float4*)(out + (size_t)row * 256))[lane] = rr;
}

// ---------------------------------------------------------------------------
extern "C" void kernel_launch(void* const* d_in, const int* in_sizes, int n_in,
                              void* d_out, int out_size, void* d_ws, size_t ws_size,
                              hipStream_t stream) {
    (void)in_sizes; (void)n_in; (void)out_size; (void)ws_size;
    const float* x     = (const float*)d_in[0];
    const float* Wproj = (const float*)d_in[1];
    const float* bproj = (const float*)d_in[2];
    const float* Wih_f = (const float*)d_in[3];
    const float* Whh_f = (const float*)d_in[4];
    const float* b_f   = (const float*)d_in[5];
    const float* Wih_b = (const float*)d_in[6];
    const float* Whh_b = (const float*)d_in[7];
    const float* b_b   = (const float*)d_in[8];
    const float* gamma = (const float*)d_in[9];
    const float* beta  = (const float*)d_in[10];
    float* out = (float*)d_out;

    // workspace layout (hs reuses xbt's region: xbt dead after gemm_pre)
    char* ws = (char*)d_ws;
    unsigned short* pre  = (unsigned short*)ws;                   // 65536*1024*2 = 134217728
    unsigned short* xbt  = (unsigned short*)(ws + 134217728);     // 65536*256*2  =  33554432
    unsigned short* hs   = xbt;                                   // alias, 65536*256*2
    unsigned short* weff = (unsigned short*)(ws + 167772160);     // 1024*256*2   =    524288
    float*          beff = (float*)(ws + 168296448);              // 1024*4

    convert_kernel<<<16384, 256, 0, stream>>>(x, xbt);
    fold_kernel<<<1024, 256, 0, stream>>>(Wproj, bproj, Wih_f, b_f, Wih_b, b_b, weff, beff);
    gemm_pre<<<dim3(8, 512), 256, 0, stream>>>(xbt, weff, beff, pre);
    scan_kernel<<<dim3(128, 2), 256, 0, stream>>>(pre, Whh_f, Whh_b, hs);
    ln_kernel<<<16384, 256, 0, stream>>>(hs, out, gamma, beta);
}

// Round 16
// 363.247 us; speedup vs baseline: 1.1646x; 1.1646x over previous
//
#include <hip/hip_runtime.h>

// Problem constants: B=128, L=512, D=256, H=128, 4H=512, both dirs fused NG=1024
#define NB 128
#define NL 512
#define ND 256
#define NG 1024

typedef __attribute__((ext_vector_type(8))) short bfv8;
typedef __attribute__((ext_vector_type(4))) float f32x4;

#define LOG2E 1.4426950408889634f
#define NSCALE (-1.4426950408889634f)   // i,f,o gate rows: t = -x*log2e
#define GSCALE (2.8853900817779268f)    // g gate rows: t = 2x*log2e

__device__ __forceinline__ unsigned short f2bf(float f) {
    unsigned u = __float_as_uint(f);
    u += 0x7fffu + ((u >> 16) & 1u);   // round-to-nearest-even
    return (unsigned short)(u >> 16);
}
__device__ __forceinline__ float bf2f(unsigned short u) {
    return __uint_as_float(((unsigned)u) << 16);
}

// ---------------------------------------------------------------------------
// 1) convert+transpose: xbt[l*128+b][d] = bf16(x[b][l][d])
// ---------------------------------------------------------------------------
__global__ __launch_bounds__(256) void convert_kernel(const float* __restrict__ x,
                                                      unsigned short* __restrict__ xbt) {
    size_t t = (size_t)blockIdx.x * 256 + threadIdx.x;
    size_t e = t * 4;                       // flat idx into x, 4 floats per thread
    int d = (int)(e & 255u);
    int l = (int)((e >> 8) & 511u);
    int b = (int)(e >> 17);
    float4 v = *(const float4*)(x + e);
    ushort4 o;
    o.x = f2bf(v.x); o.y = f2bf(v.y); o.z = f2bf(v.z); o.w = f2bf(v.w);
    *(ushort4*)(xbt + ((size_t)(l * NB + b)) * ND + d) = o;
}

// ---------------------------------------------------------------------------
// 2) fold: Weff[g][k] = scale(g) * sum_d Wih[row(g)][d] * W_proj[d][k]
//    Rows reordered g = dir*512 + hid*4 + gate; gate order i,f,g,o.
//    EXP2-DOMAIN scaling folded in: i,f,o rows x(-log2e), g rows x(+2 log2e)
// ---------------------------------------------------------------------------
__global__ __launch_bounds__(256) void fold_kernel(const float* __restrict__ Wproj,
                                                   const float* __restrict__ bproj,
                                                   const float* __restrict__ Wih_f,
                                                   const float* __restrict__ b_f,
                                                   const float* __restrict__ Wih_b,
                                                   const float* __restrict__ b_b,
                                                   unsigned short* __restrict__ weff,
                                                   float* __restrict__ beff) {
    int g = blockIdx.x;            // 0..1023 (reordered output row)
    int k = threadIdx.x;           // 0..255
    int dirg = g >> 9;
    int rem  = g & 511;
    int hidg = rem >> 2;
    int gate = rem & 3;
    int srcrow = gate * 128 + hidg;
    float scale = (gate == 2) ? GSCALE : NSCALE;
    const float* Wih = dirg ? (Wih_b + (size_t)srcrow * ND) : (Wih_f + (size_t)srcrow * ND);
    float acc = 0.f;
    for (int d = 0; d < ND; ++d)
        acc += Wih[d] * Wproj[(size_t)d * ND + k];
    weff[(size_t)g * ND + k] = f2bf(acc * scale);
    if (k == 0) {
        float ab = dirg ? b_b[srcrow] : b_f[srcrow];
        for (int d = 0; d < ND; ++d) ab += Wih[d] * bproj[d];
        beff[g] = ab * scale;
    }
}

// ---------------------------------------------------------------------------
// 3) pre-GEMM: C[r][g] = bf16( A[r][:] . Bw[g][:] + bias[g] )
//    128x128 tile, BK=32, 4 waves (2x2), 16x16x32 bf16 MFMA, XOR-swizzled LDS
// ---------------------------------------------------------------------------
__global__ __launch_bounds__(256, 2) void gemm_pre(const unsigned short* __restrict__ A,
                                                   const unsigned short* __restrict__ Bw,
                                                   const float* __restrict__ bias,
                                                   unsigned short* __restrict__ C) {
    __shared__ unsigned short As[128 * 32];
    __shared__ unsigned short Bs[128 * 32];
    const int tid = threadIdx.x;
    const int lane = tid & 63;
    const int wid = tid >> 6;
    const int m0 = blockIdx.y * 128;
    const int n0 = blockIdx.x * 128;
    const int wm = (wid >> 1) * 64;
    const int wn = (wid & 1) * 64;

    f32x4 acc[4][4] = {};

    const int row0 = tid >> 2;               // 0..63
    const int row1 = row0 + 64;
    const int co = (tid & 3) * 8;            // element col offset (8 bf16 = 16B)
    const int sw = (((tid & 3) << 4) ^ ((row0 & 3) << 4)) >> 1;

    bfv8 ra0 = *(const bfv8*)(A + (size_t)(m0 + row0) * ND + co);
    bfv8 ra1 = *(const bfv8*)(A + (size_t)(m0 + row1) * ND + co);
    bfv8 rb0 = *(const bfv8*)(Bw + (size_t)(n0 + row0) * ND + co);
    bfv8 rb1 = *(const bfv8*)(Bw + (size_t)(n0 + row1) * ND + co);

    for (int it = 0; it < 8; ++it) {
        __syncthreads();
        *(bfv8*)(As + row0 * 32 + sw) = ra0;
        *(bfv8*)(As + row1 * 32 + sw) = ra1;
        *(bfv8*)(Bs + row0 * 32 + sw) = rb0;
        *(bfv8*)(Bs + row1 * 32 + sw) = rb1;
        const int k1 = ((it + 1) & 7) * 32;
        ra0 = *(const bfv8*)(A + (size_t)(m0 + row0) * ND + k1 + co);
        ra1 = *(const bfv8*)(A + (size_t)(m0 + row1) * ND + k1 + co);
        rb0 = *(const bfv8*)(Bw + (size_t)(n0 + row0) * ND + k1 + co);
        rb1 = *(const bfv8*)(Bw + (size_t)(n0 + row1) * ND + k1 + co);
        __syncthreads();

        const int r = lane & 15;
        const int kq = lane >> 4;
        bfv8 af[4], bfr[4];
        #pragma unroll
        for (int m = 0; m < 4; ++m) {
            int rw = wm + m * 16 + r;
            af[m] = *(const bfv8*)(As + rw * 32 + (((kq << 4) ^ ((rw & 3) << 4)) >> 1));
        }
        #pragma unroll
        for (int n = 0; n < 4; ++n) {
            int rw = wn + n * 16 + r;
            bfr[n] = *(const bfv8*)(Bs + rw * 32 + (((kq << 4) ^ ((rw & 3) << 4)) >> 1));
        }
        #pragma unroll
        for (int m = 0; m < 4; ++m)
            #pragma unroll
            for (int n = 0; n < 4; ++n)
                acc[m][n] = __builtin_amdgcn_mfma_f32_16x16x32_bf16(af[m], bfr[n], acc[m][n], 0, 0, 0);
    }

    const int r = lane & 15;
    const int rq = lane >> 4;
    #pragma unroll
    for (int n = 0; n < 4; ++n) {
        int col = n0 + wn + n * 16 + r;
        float bv = bias[col];
        #pragma unroll
        for (int m = 0; m < 4; ++m) {
            #pragma unroll
            for (int v = 0; v < 4; ++v) {
                int rowg = m0 + wm + m * 16 + rq * 4 + v;
                C[(size_t)rowg * NG + col] = f2bf(acc[m][n][v] + bv);
            }
        }
    }
}

// ---------------------------------------------------------------------------
// 4) LSTM scan: REVERT to r14's 512-thread / 8-wave structure (2 chain-waves
//    per SIMD = the measured sweet spot of issue vs chain-exposure; r15's
//    1-wave/SIMD exposed the full serial chain and regressed 259->327us).
//    Plus two safe cuts vs r14:
//    (a) h stored bf16 to hs workspace (ln reads bf16): halves store bytes,
//        -64MB ln traffic.
//    (b) split-tree MFMA accumulation: each gate = two parallel 2-deep MFMA
//        chains + scalar add (iA[0]+iB[0]) -> halves exposed MFMA dep depth.
//    Keeps: wave w owns cols {g*128+16w+r} (i,f,g,o of hid in same lane,
//    zero shuffles), 16x A-replication (broadcast ds_read), B-frags
//    persistent, exp2/rcp lean ACT, saddr+v_off depth-2 prefetch, ONE raw
//    barrier/step (counted vmcnt), LDS pin >80KiB -> 1 block/CU.
// ---------------------------------------------------------------------------
struct ScanSM {
    unsigned short h[2][136];      // [buf][hid] bf16
    char pin[81700];               // total 82244 B > 81920 -> 1 block/CU
};

#define MFMA16(a, b, c) __builtin_amdgcn_mfma_f32_16x16x32_bf16((a), (b), (c), 0, 0, 0)

#define STEP(S, CURB, NXTB)                                                    \
  {                                                                            \
    int rr = (S) + 2; if (rr > 511) rr = 511;          /* uniform SALU */      \
    int tts = dirs ? (511 - rr) : rr;                                          \
    const unsigned short* rowp = pdb + (size_t)tts * (NB * NG);                \
    uint2 nx = *(const uint2*)(rowp + hid4);           /* saddr + v_off */     \
    bfv8 ha0 = *(const bfv8*)&sm.h[CURB][q * 8];                               \
    bfv8 ha1 = *(const bfv8*)&sm.h[CURB][32 + q * 8];                          \
    bfv8 ha2 = *(const bfv8*)&sm.h[CURB][64 + q * 8];                          \
    bfv8 ha3 = *(const bfv8*)&sm.h[CURB][96 + q * 8];                          \
    f32x4 z = {0.f, 0.f, 0.f, 0.f};                                            \
    f32x4 iA = MFMA16(ha0, bfr[0][0], z);                                      \
    f32x4 fA = MFMA16(ha0, bfr[1][0], z);                                      \
    f32x4 gA = MFMA16(ha0, bfr[2][0], z);                                      \
    f32x4 oA = MFMA16(ha0, bfr[3][0], z);                                      \
    f32x4 iB = MFMA16(ha2, bfr[0][2], z);                                      \
    f32x4 fB = MFMA16(ha2, bfr[1][2], z);                                      \
    f32x4 gB = MFMA16(ha2, bfr[2][2], z);                                      \
    f32x4 oB = MFMA16(ha2, bfr[3][2], z);                                      \
    iA = MFMA16(ha1, bfr[0][1], iA); fA = MFMA16(ha1, bfr[1][1], fA);          \
    gA = MFMA16(ha1, bfr[2][1], gA); oA = MFMA16(ha1, bfr[3][1], oA);          \
    iB = MFMA16(ha3, bfr[0][3], iB); fB = MFMA16(ha3, bfr[1][3], fB);          \
    gB = MFMA16(ha3, bfr[2][3], gB); oB = MFMA16(ha3, bfr[3][3], oB);          \
    int tt = dirs ? (511 - (S)) : (S);                                         \
    {                                                                          \
        float pi = __uint_as_float(pP0.x << 16);                               \
        float pf = __uint_as_float(pP0.x & 0xffff0000u);                       \
        float pg = __uint_as_float(pP0.y << 16);                               \
        float po = __uint_as_float(pP0.y & 0xffff0000u);                       \
        /* scaled domain: t_ifo = -x*log2e, t_g = 2x*log2e (folded) */         \
        float ia = __builtin_amdgcn_rcpf(1.f + __builtin_amdgcn_exp2f(iA[0] + iB[0] + pi)); \
        float fa = __builtin_amdgcn_rcpf(1.f + __builtin_amdgcn_exp2f(fA[0] + fB[0] + pf)); \
        float rg = __builtin_amdgcn_rcpf(1.f + __builtin_amdgcn_exp2f(gA[0] + gB[0] + pg)); \
        float oa = __builtin_amdgcn_rcpf(1.f + __builtin_amdgcn_exp2f(oA[0] + oB[0] + po)); \
        float ga = fmaf(-2.f, rg, 1.f);                                        \
        c0 = fmaf(fa, c0, ia * ga);                                            \
        float rc = __builtin_amdgcn_rcpf(1.f + __builtin_amdgcn_exp2f(c0 * GSCALE)); \
        float th = fmaf(-2.f, rc, 1.f);                                        \
        unsigned short us = f2bf(oa * th);                                     \
        if (q == 0) {                                                          \
            sm.h[NXTB][hid] = us;                                              \
            hsrow[(size_t)tt * 256 + hid] = us;                                \
        }                                                                      \
    }                                                                          \
    pP0 = pP1; pP1 = nx;                                                       \
    __builtin_amdgcn_sched_barrier(0);                                         \
    asm volatile("s_waitcnt lgkmcnt(0)");                                      \
    __builtin_amdgcn_s_barrier();                                              \
    __builtin_amdgcn_sched_barrier(0);                                         \
  }

__global__ void __launch_bounds__(512)
scan_kernel(const unsigned short* __restrict__ pre,
            const float* __restrict__ Whh_f,
            const float* __restrict__ Whh_b,
            unsigned short* __restrict__ hs) {
    const int b    = blockIdx.x;         // batch 0..127
    const int dirs = blockIdx.y;         // 0 fwd, 1 bwd (kernel-scalar)
    const int tid  = threadIdx.x;
    const int w    = tid >> 6;           // hid group: cols 16w..16w+15
    const int lane = tid & 63;
    const int r    = lane & 15;          // frag col -> hid sub-index
    const int q    = lane >> 4;          // frag k-group
    const int hid  = 16 * w + r;
    const int hid4 = hid * 4;            // element offset of lane's uint2

    __shared__ ScanSM sm;

    // ---- persistent B-fragments: Whh (f32) -> bf16 with exp2-domain scale --
    const float* __restrict__ Wd = dirs ? Whh_b : Whh_f;
    bfv8 bfr[4][4];                      // [gate][ktile]
    #pragma unroll
    for (int g = 0; g < 4; ++g) {
        const float wscale = (g == 2) ? GSCALE : NSCALE;
        #pragma unroll
        for (int kk = 0; kk < 4; ++kk) {
            const float* src = Wd + (size_t)(g * 128 + hid) * 128 + kk * 32 + q * 8;
            float4 lo = *(const float4*)(src);
            float4 hi = *(const float4*)(src + 4);
            bfv8 v;
            v[0] = (short)f2bf(lo.x * wscale); v[1] = (short)f2bf(lo.y * wscale);
            v[2] = (short)f2bf(lo.z * wscale); v[3] = (short)f2bf(lo.w * wscale);
            v[4] = (short)f2bf(hi.x * wscale); v[5] = (short)f2bf(hi.y * wscale);
            v[6] = (short)f2bf(hi.z * wscale); v[7] = (short)f2bf(hi.w * wscale);
            bfr[g][kk] = v;
        }
    }

    // ---- zero h buf 0 ----
    if (q == 0) sm.h[0][hid] = 0;

    float c0 = 0.f;

    // ---- uniform bases: pre row base (dir half), hs batch base ----
    const unsigned short* pdb = pre + (size_t)b * NG + dirs * 512;
    unsigned short* hsrow = hs + (size_t)b * NL * 256 + dirs * 128;

    int t0 = dirs ? 511 : 0;
    int t1 = dirs ? 510 : 1;
    uint2 pP0 = *(const uint2*)(pdb + (size_t)t0 * (NB * NG) + hid4);
    uint2 pP1 = *(const uint2*)(pdb + (size_t)t1 * (NB * NG) + hid4);
    __syncthreads();

    for (int s = 0; s < 512; s += 2) {
        STEP(s, 0, 1)
        STEP(s + 1, 1, 0)
    }
}

// ---------------------------------------------------------------------------
// 5) LayerNorm: read bf16 hs, write f32 out; one wave per 256-wide row
// ---------------------------------------------------------------------------
__global__ __launch_bounds__(256) void ln_kernel(const unsigned short* __restrict__ hs,
                                                 float* __restrict__ out,
                                                 const float* __restrict__ gamma,
                                                 const float* __restrict__ beta) {
    int row = blockIdx.x * 4 + (threadIdx.x >> 6);
    int lane = threadIdx.x & 63;
    const ushort4 hv = ((const ushort4*)(hs + (size_t)row * 256))[lane];
    float a = bf2f(hv.x), bb = bf2f(hv.y), c = bf2f(hv.z), d = bf2f(hv.w);
    float s = (a + bb) + (c + d);
    float s2 = (a * a + bb * bb) + (c * c + d * d);
    #pragma unroll
    for (int o = 32; o > 0; o >>= 1) {
        s += __shfl_xor(s, o);
        s2 += __shfl_xor(s2, o);
    }
    float mu = s * (1.f / 256.f);
    float var = s2 * (1.f / 256.f) - mu * mu;
    float rs = rsqrtf(var + 1e-5f);
    float4 gv = ((const float4*)gamma)[lane];
    float4 bv = ((const float4*)beta)[lane];
    float4 rr;
    rr.x = (a - mu) * rs * gv.x + bv.x;
    rr.y = (bb - mu) * rs * gv.y + bv.y;
    rr.z = (c - mu) * rs * gv.z + bv.z;
    rr.w = (d - mu) * rs * gv.w + bv.w;
    ((float4*)(out + (size_t)row * 256))[lane] = rr;
}

// ---------------------------------------------------------------------------
extern "C" void kernel_launch(void* const* d_in, const int* in_sizes, int n_in,
                              void* d_out, int out_size, void* d_ws, size_t ws_size,
                              hipStream_t stream) {
    (void)in_sizes; (void)n_in; (void)out_size; (void)ws_size;
    const float* x     = (const float*)d_in[0];
    const float* Wproj = (const float*)d_in[1];
    const float* bproj = (const float*)d_in[2];
    const float* Wih_f = (const float*)d_in[3];
    const float* Whh_f = (const float*)d_in[4];
    const float* b_f   = (const float*)d_in[5];
    const float* Wih_b = (const float*)d_in[6];
    const float* Whh_b = (const float*)d_in[7];
    const float* b_b   = (const float*)d_in[8];
    const float* gamma = (const float*)d_in[9];
    const float* beta  = (const float*)d_in[10];
    float* out = (float*)d_out;

    // workspace layout (hs reuses xbt's region: xbt dead after gemm_pre)
    char* ws = (char*)d_ws;
    unsigned short* pre  = (unsigned short*)ws;                   // 65536*1024*2 = 134217728
    unsigned short* xbt  = (unsigned short*)(ws + 134217728);     // 65536*256*2  =  33554432
    unsigned short* hs   = xbt;                                   // alias, 65536*256*2
    unsigned short* weff = (unsigned short*)(ws + 167772160);     // 1024*256*2   =    524288
    float*          beff = (float*)(ws + 168296448);              // 1024*4

    convert_kernel<<<16384, 256, 0, stream>>>(x, xbt);
    fold_kernel<<<1024, 256, 0, stream>>>(Wproj, bproj, Wih_f, b_f, Wih_b, b_b, weff, beff);
    gemm_pre<<<dim3(8, 512), 256, 0, stream>>>(xbt, weff, beff, pre);
    scan_kernel<<<dim3(128, 2), 512, 0, stream>>>(pre, Whh_f, Whh_b, hs);
    ln_kernel<<<16384, 256, 0, stream>>>(hs, out, gamma, beta);
}

// Round 17
// 363.142 us; speedup vs baseline: 1.1650x; 1.0003x over previous
//
#include <hip/hip_runtime.h>

// Problem constants: B=128, L=512, D=256, H=128, 4H=512, both dirs fused NG=1024
#define NB 128
#define NL 512
#define ND 256
#define NG 1024

typedef __attribute__((ext_vector_type(8))) short bfv8;
typedef __attribute__((ext_vector_type(4))) float f32x4;

typedef __attribute__((address_space(1))) const unsigned int glo_u32;
typedef __attribute__((address_space(3))) unsigned int lds_u32;

#define LOG2E 1.4426950408889634f
#define NSCALE (-1.4426950408889634f)   // i,f,o gate rows: t = -x*log2e
#define GSCALE (2.8853900817779268f)    // g gate rows: t = 2x*log2e

__device__ __forceinline__ unsigned short f2bf(float f) {
    unsigned u = __float_as_uint(f);
    u += 0x7fffu + ((u >> 16) & 1u);   // round-to-nearest-even
    return (unsigned short)(u >> 16);
}
__device__ __forceinline__ float bf2f(unsigned short u) {
    return __uint_as_float(((unsigned)u) << 16);
}

// ---------------------------------------------------------------------------
// 1) convert+transpose: xbt[l*128+b][d] = bf16(x[b][l][d])
// ---------------------------------------------------------------------------
__global__ __launch_bounds__(256) void convert_kernel(const float* __restrict__ x,
                                                      unsigned short* __restrict__ xbt) {
    size_t t = (size_t)blockIdx.x * 256 + threadIdx.x;
    size_t e = t * 4;                       // flat idx into x, 4 floats per thread
    int d = (int)(e & 255u);
    int l = (int)((e >> 8) & 511u);
    int b = (int)(e >> 17);
    float4 v = *(const float4*)(x + e);
    ushort4 o;
    o.x = f2bf(v.x); o.y = f2bf(v.y); o.z = f2bf(v.z); o.w = f2bf(v.w);
    *(ushort4*)(xbt + ((size_t)(l * NB + b)) * ND + d) = o;
}

// ---------------------------------------------------------------------------
// 2) fold: Weff[g][k] = scale(g) * sum_d Wih[row(g)][d] * W_proj[d][k]
//    Rows reordered g = dir*512 + hid*4 + gate; gate order i,f,g,o.
//    EXP2-DOMAIN scaling folded in: i,f,o rows x(-log2e), g rows x(+2 log2e)
// ---------------------------------------------------------------------------
__global__ __launch_bounds__(256) void fold_kernel(const float* __restrict__ Wproj,
                                                   const float* __restrict__ bproj,
                                                   const float* __restrict__ Wih_f,
                                                   const float* __restrict__ b_f,
                                                   const float* __restrict__ Wih_b,
                                                   const float* __restrict__ b_b,
                                                   unsigned short* __restrict__ weff,
                                                   float* __restrict__ beff) {
    int g = blockIdx.x;            // 0..1023 (reordered output row)
    int k = threadIdx.x;           // 0..255
    int dirg = g >> 9;
    int rem  = g & 511;
    int hidg = rem >> 2;
    int gate = rem & 3;
    int srcrow = gate * 128 + hidg;
    float scale = (gate == 2) ? GSCALE : NSCALE;
    const float* Wih = dirg ? (Wih_b + (size_t)srcrow * ND) : (Wih_f + (size_t)srcrow * ND);
    float acc = 0.f;
    for (int d = 0; d < ND; ++d)
        acc += Wih[d] * Wproj[(size_t)d * ND + k];
    weff[(size_t)g * ND + k] = f2bf(acc * scale);
    if (k == 0) {
        float ab = dirg ? b_b[srcrow] : b_f[srcrow];
        for (int d = 0; d < ND; ++d) ab += Wih[d] * bproj[d];
        beff[g] = ab * scale;
    }
}

// ---------------------------------------------------------------------------
// 3) pre-GEMM: C[r][g] = bf16( A[r][:] . Bw[g][:] + bias[g] )
//    128x128 tile, BK=32, 4 waves (2x2), 16x16x32 bf16 MFMA.
//    NOW: global_load_lds width-16 staging (m97 pattern, +67% vs reg-staged).
//    Rule #21: LDS dest linear (wave-uniform base + lane*16), XOR swizzle
//    moved to the SOURCE chunk ((lane&3)^(row&3)); read side unchanged —
//    same involution on both sides.
// ---------------------------------------------------------------------------
__global__ __launch_bounds__(256, 2) void gemm_pre(const unsigned short* __restrict__ A,
                                                   const unsigned short* __restrict__ Bw,
                                                   const float* __restrict__ bias,
                                                   unsigned short* __restrict__ C) {
    __shared__ unsigned short As[128 * 32];
    __shared__ unsigned short Bs[128 * 32];
    const int tid = threadIdx.x;
    const int lane = tid & 63;
    const int wid = tid >> 6;
    const int m0 = blockIdx.y * 128;
    const int n0 = blockIdx.x * 128;
    const int wm = (wid >> 1) * 64;
    const int wn = (wid & 1) * 64;

    f32x4 acc[4][4] = {};

    // staging: wave wid covers rows 16*wid+(lane>>2) (call 0) and +64 (call 1)
    const int srow = tid >> 2;                 // = 16*wid + (lane>>2), 0..63
    const int csrc = (lane & 3) ^ (srow & 3);  // pre-swizzled source chunk
    // wave-uniform LDS bases (ushort units): 1KB per wave-call
    unsigned short* a_l0 = As + wid * 512;
    unsigned short* a_l1 = As + 2048 + wid * 512;
    unsigned short* b_l0 = Bs + wid * 512;
    unsigned short* b_l1 = Bs + 2048 + wid * 512;

    for (int it = 0; it < 8; ++it) {
        __syncthreads();                       // prior compute done; LDS reusable
        const int kb = it * 32;
        const unsigned short* ga0 = A  + (size_t)(m0 + srow) * ND + kb + csrc * 8;
        const unsigned short* ga1 = A  + (size_t)(m0 + srow + 64) * ND + kb + csrc * 8;
        const unsigned short* gb0 = Bw + (size_t)(n0 + srow) * ND + kb + csrc * 8;
        const unsigned short* gb1 = Bw + (size_t)(n0 + srow + 64) * ND + kb + csrc * 8;
        __builtin_amdgcn_global_load_lds((glo_u32*)ga0, (lds_u32*)a_l0, 16, 0, 0);
        __builtin_amdgcn_global_load_lds((glo_u32*)ga1, (lds_u32*)a_l1, 16, 0, 0);
        __builtin_amdgcn_global_load_lds((glo_u32*)gb0, (lds_u32*)b_l0, 16, 0, 0);
        __builtin_amdgcn_global_load_lds((glo_u32*)gb1, (lds_u32*)b_l1, 16, 0, 0);
        __syncthreads();                       // vmcnt(0) drained -> tile ready

        const int r = lane & 15;
        const int kq = lane >> 4;
        bfv8 af[4], bfr[4];
        #pragma unroll
        for (int m = 0; m < 4; ++m) {
            int rw = wm + m * 16 + r;
            af[m] = *(const bfv8*)(As + rw * 32 + ((((kq << 4) ^ ((rw & 3) << 4))) >> 1));
        }
        #pragma unroll
        for (int n = 0; n < 4; ++n) {
            int rw = wn + n * 16 + r;
            bfr[n] = *(const bfv8*)(Bs + rw * 32 + ((((kq << 4) ^ ((rw & 3) << 4))) >> 1));
        }
        #pragma unroll
        for (int m = 0; m < 4; ++m)
            #pragma unroll
            for (int n = 0; n < 4; ++n)
                acc[m][n] = __builtin_amdgcn_mfma_f32_16x16x32_bf16(af[m], bfr[n], acc[m][n], 0, 0, 0);
    }

    const int r = lane & 15;
    const int rq = lane >> 4;
    #pragma unroll
    for (int n = 0; n < 4; ++n) {
        int col = n0 + wn + n * 16 + r;
        float bv = bias[col];
        #pragma unroll
        for (int m = 0; m < 4; ++m) {
            #pragma unroll
            for (int v = 0; v < 4; ++v) {
                int rowg = m0 + wm + m * 16 + rq * 4 + v;
                C[(size_t)rowg * NG + col] = f2bf(acc[m][n][v] + bv);
            }
        }
    }
}

// ---------------------------------------------------------------------------
// 4) LSTM scan: r14 structure EXACTLY (512 thr / 8 waves / 2 chain-waves per
//    SIMD = measured sweet spot; 4-deep MFMA chains — r16's split-tree cost
//    +8us of issue with no latency win, reverted) + bf16 hs store (r15/r16's
//    one good part: halves store bytes, ln reads bf16).
//    Keeps: wave w owns cols {g*128+16w+r} (i,f,g,o of hid in same lane,
//    zero shuffles), 16x A-replication (broadcast ds_read), B-frags
//    persistent, exp2/rcp lean ACT, saddr+v_off depth-2 prefetch, ONE raw
//    barrier/step (counted vmcnt), LDS pin >80KiB -> 1 block/CU.
// ---------------------------------------------------------------------------
struct ScanSM {
    unsigned short h[2][136];      // [buf][hid] bf16
    char pin[81700];               // total 82244 B > 81920 -> 1 block/CU
};

#define MFMA16(a, b, c) __builtin_amdgcn_mfma_f32_16x16x32_bf16((a), (b), (c), 0, 0, 0)

#define STEP(S, CURB, NXTB)                                                    \
  {                                                                            \
    int rr = (S) + 2; if (rr > 511) rr = 511;          /* uniform SALU */      \
    int tts = dirs ? (511 - rr) : rr;                                          \
    const unsigned short* rowp = pdb + (size_t)tts * (NB * NG);                \
    uint2 nx = *(const uint2*)(rowp + hid4);           /* saddr + v_off */     \
    bfv8 ha0 = *(const bfv8*)&sm.h[CURB][q * 8];                               \
    bfv8 ha1 = *(const bfv8*)&sm.h[CURB][32 + q * 8];                          \
    bfv8 ha2 = *(const bfv8*)&sm.h[CURB][64 + q * 8];                          \
    bfv8 ha3 = *(const bfv8*)&sm.h[CURB][96 + q * 8];                          \
    f32x4 z = {0.f, 0.f, 0.f, 0.f};                                            \
    f32x4 acci = MFMA16(ha0, bfr[0][0], z);                                    \
    f32x4 accf = MFMA16(ha0, bfr[1][0], z);                                    \
    f32x4 accg = MFMA16(ha0, bfr[2][0], z);                                    \
    f32x4 acco = MFMA16(ha0, bfr[3][0], z);                                    \
    acci = MFMA16(ha1, bfr[0][1], acci); accf = MFMA16(ha1, bfr[1][1], accf);  \
    accg = MFMA16(ha1, bfr[2][1], accg); acco = MFMA16(ha1, bfr[3][1], acco);  \
    acci = MFMA16(ha2, bfr[0][2], acci); accf = MFMA16(ha2, bfr[1][2], accf);  \
    accg = MFMA16(ha2, bfr[2][2], accg); acco = MFMA16(ha2, bfr[3][2], acco);  \
    acci = MFMA16(ha3, bfr[0][3], acci); accf = MFMA16(ha3, bfr[1][3], accf);  \
    accg = MFMA16(ha3, bfr[2][3], accg); acco = MFMA16(ha3, bfr[3][3], acco);  \
    int tt = dirs ? (511 - (S)) : (S);                                         \
    {                                                                          \
        float pi = __uint_as_float(pP0.x << 16);                               \
        float pf = __uint_as_float(pP0.x & 0xffff0000u);                       \
        float pg = __uint_as_float(pP0.y << 16);                               \
        float po = __uint_as_float(pP0.y & 0xffff0000u);                       \
        /* scaled domain: t_ifo = -x*log2e, t_g = 2x*log2e (folded) */         \
        float ia = __builtin_amdgcn_rcpf(1.f + __builtin_amdgcn_exp2f(acci[0] + pi)); \
        float fa = __builtin_amdgcn_rcpf(1.f + __builtin_amdgcn_exp2f(accf[0] + pf)); \
        float rg = __builtin_amdgcn_rcpf(1.f + __builtin_amdgcn_exp2f(accg[0] + pg)); \
        float oa = __builtin_amdgcn_rcpf(1.f + __builtin_amdgcn_exp2f(acco[0] + po)); \
        float ga = fmaf(-2.f, rg, 1.f);                                        \
        c0 = fmaf(fa, c0, ia * ga);                                            \
        float rc = __builtin_amdgcn_rcpf(1.f + __builtin_amdgcn_exp2f(c0 * GSCALE)); \
        float th = fmaf(-2.f, rc, 1.f);                                        \
        unsigned short us = f2bf(oa * th);                                     \
        if (q == 0) {                                                          \
            sm.h[NXTB][hid] = us;                                              \
            hsrow[(size_t)tt * 256 + hid] = us;                                \
        }                                                                      \
    }                                                                          \
    pP0 = pP1; pP1 = nx;                                                       \
    __builtin_amdgcn_sched_barrier(0);                                         \
    asm volatile("s_waitcnt lgkmcnt(0)");                                      \
    __builtin_amdgcn_s_barrier();                                              \
    __builtin_amdgcn_sched_barrier(0);                                         \
  }

__global__ void __launch_bounds__(512)
scan_kernel(const unsigned short* __restrict__ pre,
            const float* __restrict__ Whh_f,
            const float* __restrict__ Whh_b,
            unsigned short* __restrict__ hs) {
    const int b    = blockIdx.x;         // batch 0..127
    const int dirs = blockIdx.y;         // 0 fwd, 1 bwd (kernel-scalar)
    const int tid  = threadIdx.x;
    const int w    = tid >> 6;           // hid group: cols 16w..16w+15
    const int lane = tid & 63;
    const int r    = lane & 15;          // frag col -> hid sub-index
    const int q    = lane >> 4;          // frag k-group
    const int hid  = 16 * w + r;
    const int hid4 = hid * 4;            // element offset of lane's uint2

    __shared__ ScanSM sm;

    // ---- persistent B-fragments: Whh (f32) -> bf16 with exp2-domain scale --
    const float* __restrict__ Wd = dirs ? Whh_b : Whh_f;
    bfv8 bfr[4][4];                      // [gate][ktile]
    #pragma unroll
    for (int g = 0; g < 4; ++g) {
        const float wscale = (g == 2) ? GSCALE : NSCALE;
        #pragma unroll
        for (int kk = 0; kk < 4; ++kk) {
            const float* src = Wd + (size_t)(g * 128 + hid) * 128 + kk * 32 + q * 8;
            float4 lo = *(const float4*)(src);
            float4 hi = *(const float4*)(src + 4);
            bfv8 v;
            v[0] = (short)f2bf(lo.x * wscale); v[1] = (short)f2bf(lo.y * wscale);
            v[2] = (short)f2bf(lo.z * wscale); v[3] = (short)f2bf(lo.w * wscale);
            v[4] = (short)f2bf(hi.x * wscale); v[5] = (short)f2bf(hi.y * wscale);
            v[6] = (short)f2bf(hi.z * wscale); v[7] = (short)f2bf(hi.w * wscale);
            bfr[g][kk] = v;
        }
    }

    // ---- zero h buf 0 ----
    if (q == 0) sm.h[0][hid] = 0;

    float c0 = 0.f;

    // ---- uniform bases: pre row base (dir half), hs batch base ----
    const unsigned short* pdb = pre + (size_t)b * NG + dirs * 512;
    unsigned short* hsrow = hs + (size_t)b * NL * 256 + dirs * 128;

    int t0 = dirs ? 511 : 0;
    int t1 = dirs ? 510 : 1;
    uint2 pP0 = *(const uint2*)(pdb + (size_t)t0 * (NB * NG) + hid4);
    uint2 pP1 = *(const uint2*)(pdb + (size_t)t1 * (NB * NG) + hid4);
    __syncthreads();

    for (int s = 0; s < 512; s += 2) {
        STEP(s, 0, 1)
        STEP(s + 1, 1, 0)
    }
}

// ---------------------------------------------------------------------------
// 5) LayerNorm: read bf16 hs, write f32 out; one wave per 256-wide row
// ---------------------------------------------------------------------------
__global__ __launch_bounds__(256) void ln_kernel(const unsigned short* __restrict__ hs,
                                                 float* __restrict__ out,
                                                 const float* __restrict__ gamma,
                                                 const float* __restrict__ beta) {
    int row = blockIdx.x * 4 + (threadIdx.x >> 6);
    int lane = threadIdx.x & 63;
    const ushort4 hv = ((const ushort4*)(hs + (size_t)row * 256))[lane];
    float a = bf2f(hv.x), bb = bf2f(hv.y), c = bf2f(hv.z), d = bf2f(hv.w);
    float s = (a + bb) + (c + d);
    float s2 = (a * a + bb * bb) + (c * c + d * d);
    #pragma unroll
    for (int o = 32; o > 0; o >>= 1) {
        s += __shfl_xor(s, o);
        s2 += __shfl_xor(s2, o);
    }
    float mu = s * (1.f / 256.f);
    float var = s2 * (1.f / 256.f) - mu * mu;
    float rs = rsqrtf(var + 1e-5f);
    float4 gv = ((const float4*)gamma)[lane];
    float4 bv = ((const float4*)beta)[lane];
    float4 rr;
    rr.x = (a - mu) * rs * gv.x + bv.x;
    rr.y = (bb - mu) * rs * gv.y + bv.y;
    rr.z = (c - mu) * rs * gv.z + bv.z;
    rr.w = (d - mu) * rs * gv.w + bv.w;
    ((float4*)(out + (size_t)row * 256))[lane] = rr;
}

// ---------------------------------------------------------------------------
extern "C" void kernel_launch(void* const* d_in, const int* in_sizes, int n_in,
                              void* d_out, int out_size, void* d_ws, size_t ws_size,
                              hipStream_t stream) {
    (void)in_sizes; (void)n_in; (void)out_size; (void)ws_size;
    const float* x     = (const float*)d_in[0];
    const float* Wproj = (const float*)d_in[1];
    const float* bproj = (const float*)d_in[2];
    const float* Wih_f = (const float*)d_in[3];
    const float* Whh_f = (const float*)d_in[4];
    const float* b_f   = (const float*)d_in[5];
    const float* Wih_b = (const float*)d_in[6];
    const float* Whh_b = (const float*)d_in[7];
    const float* b_b   = (const float*)d_in[8];
    const float* gamma = (const float*)d_in[9];
    const float* beta  = (const float*)d_in[10];
    float* out = (float*)d_out;

    // workspace layout (hs reuses xbt's region: xbt dead after gemm_pre)
    char* ws = (char*)d_ws;
    unsigned short* pre  = (unsigned short*)ws;                   // 65536*1024*2 = 134217728
    unsigned short* xbt  = (unsigned short*)(ws + 134217728);     // 65536*256*2  =  33554432
    unsigned short* hs   = xbt;                                   // alias, 65536*256*2
    unsigned short* weff = (unsigned short*)(ws + 167772160);     // 1024*256*2   =    524288
    float*          beff = (float*)(ws + 168296448);              // 1024*4

    convert_kernel<<<16384, 256, 0, stream>>>(x, xbt);
    fold_kernel<<<1024, 256, 0, stream>>>(Wproj, bproj, Wih_f, b_f, Wih_b, b_b, weff, beff);
    gemm_pre<<<dim3(8, 512), 256, 0, stream>>>(xbt, weff, beff, pre);
    scan_kernel<<<dim3(128, 2), 512, 0, stream>>>(pre, Whh_f, Whh_b, hs);
    ln_kernel<<<16384, 256, 0, stream>>>(hs, out, gamma, beta);
}